// Round 6
// baseline (514.308 us; speedup 1.0000x reference)
//
#include <hip/hip_runtime.h>
#include <hip/hip_bf16.h>

#define M_TOK 16384   // B*S
#define DDIM  1024
#define NEXP  8
#define KP    (NEXP * DDIM)   // 8192 fused K

typedef __bf16 bf16x8 __attribute__((ext_vector_type(8)));
typedef float  floatx4 __attribute__((ext_vector_type(4)));

__device__ __forceinline__ void gload_lds16(const void* g, void* l) {
    __builtin_amdgcn_global_load_lds(
        (__attribute__((address_space(1))) void*)(void*)g,
        (__attribute__((address_space(3))) void*)l,
        16, 0, 0);
}

// ---------------------------------------------------------------------------
// Fused prep kernel (single dispatch, 6144 blocks):
//   role = blockIdx.x % 3:  {0,1} -> route/softmax/h->bf16  (4096 block-slots)
//                           {2}   -> W_edges fp32 -> B' bf16 (2048 block-slots)
// Interleaving overlaps the two independent memory streams and removes one
// launch gap vs two dispatches.
// ---------------------------------------------------------------------------
__global__ __launch_bounds__(256) void prep_kernel(
    const float* __restrict__ h, const float* __restrict__ Wr,
    const float* __restrict__ br, const float* __restrict__ We,
    __bf16* __restrict__ hbf, __bf16* __restrict__ Bp,
    float* __restrict__ rw)
{
    __shared__ float Wrs[NEXP * DDIM];   // used by route role only
    const int tid = threadIdx.x;
    const int bid = blockIdx.x;
    const int role = bid % 3;

    if (role < 2) {
        // ---------------- route + softmax + h->bf16 ----------------
        const int rbid = (bid / 3) * 2 + role;   // 0..4095
        {
            const float4* s4 = (const float4*)Wr;
            float4* d4 = (float4*)Wrs;
            #pragma unroll
            for (int j = 0; j < 8; ++j) d4[j * 256 + tid] = s4[j * 256 + tid];
        }
        __syncthreads();

        const int wave = tid >> 6, lane = tid & 63;
        const int m = rbid * 4 + wave;

        const float4* hrow = (const float4*)(h + (size_t)m * DDIM + lane * 16);
        float a[16];
        #pragma unroll
        for (int i = 0; i < 4; ++i) {
            float4 v = hrow[i];
            a[i*4+0] = v.x; a[i*4+1] = v.y; a[i*4+2] = v.z; a[i*4+3] = v.w;
        }
        bf16x8 o0, o1;
        #pragma unroll
        for (int i = 0; i < 8; ++i) { o0[i] = (__bf16)a[i]; o1[i] = (__bf16)a[8 + i]; }
        *(bf16x8*)(hbf + (size_t)m * DDIM + lane * 16)     = o0;
        *(bf16x8*)(hbf + (size_t)m * DDIM + lane * 16 + 8) = o1;

        float p[NEXP];
        #pragma unroll
        for (int e = 0; e < NEXP; ++e) {
            const float4* w4 = (const float4*)&Wrs[e * DDIM + lane * 16];
            float s = 0.f;
            #pragma unroll
            for (int i = 0; i < 4; ++i) {
                float4 wv = w4[i];
                s += a[i*4+0]*wv.x + a[i*4+1]*wv.y + a[i*4+2]*wv.z + a[i*4+3]*wv.w;
            }
            p[e] = s;
        }
        #pragma unroll
        for (int e = 0; e < NEXP; ++e) {
            #pragma unroll
            for (int off = 32; off > 0; off >>= 1)
                p[e] += __shfl_xor(p[e], off, 64);
        }
        if (lane == 0) {
            float l[NEXP], mx = -1e30f;
            #pragma unroll
            for (int e = 0; e < NEXP; ++e) { l[e] = p[e] + br[e]; mx = fmaxf(mx, l[e]); }
            float s = 0.f;
            #pragma unroll
            for (int e = 0; e < NEXP; ++e) { l[e] = expf(l[e] - mx); s += l[e]; }
            float inv = 1.f / s;
            float4 r0 = {l[0]*inv, l[1]*inv, l[2]*inv, l[3]*inv};
            float4 r1 = {l[4]*inv, l[5]*inv, l[6]*inv, l[7]*inv};
            *(float4*)(rw + (size_t)m * NEXP)     = r0;
            *(float4*)(rw + (size_t)m * NEXP + 4) = r1;
        }
    } else {
        // ---------------- W_edges [e][f][k] fp32 -> B'[f][e*1024+k] bf16 ----
        const int cbid = bid / 3;                // 0..2047
        size_t idx = ((size_t)cbid * 256 + tid) * 16;
        int e = (int)(idx >> 20);
        int f = (int)(idx >> 10) & 1023;
        int k = (int)idx & 1023;
        const float4* s4 = (const float4*)(We + idx);
        float a[16];
        #pragma unroll
        for (int i = 0; i < 4; ++i) {
            float4 v = s4[i];
            a[i*4+0] = v.x; a[i*4+1] = v.y; a[i*4+2] = v.z; a[i*4+3] = v.w;
        }
        bf16x8 o0, o1;
        #pragma unroll
        for (int i = 0; i < 8; ++i) { o0[i] = (__bf16)a[i]; o1[i] = (__bf16)a[8 + i]; }
        __bf16* d = Bp + (size_t)f * KP + (size_t)e * DDIM + k;
        *(bf16x8*)d       = o0;
        *(bf16x8*)(d + 8) = o1;
    }
}

// ---------------------------------------------------------------------------
// GEMM kernel: byte-identical structure to round 5 (745 TF, MfmaUtil 31%).
// Single-dispatch fused MoE GEMM with online expert rescaling.
// 128x128 tile, BK=64, XOR-swizzled LDS, single 64-reg facc.
// ---------------------------------------------------------------------------
__global__ __launch_bounds__(256, 3) void gemm_fused_kernel(
    const __bf16* __restrict__ hbf, const __bf16* __restrict__ Bp,
    const float* __restrict__ rw, const float* __restrict__ bias,
    float* __restrict__ outp)
{
    __shared__ __bf16 As[128 * 64];
    __shared__ __bf16 Bs[128 * 64];
    __shared__ float  rws[128 * NEXP];

    const int tid  = threadIdx.x;
    const int wave = tid >> 6, lane = tid & 63;
    const int quad = lane >> 4, l16 = lane & 15;
    const int wm = wave & 1, wn = wave >> 1;
    const int m0 = blockIdx.y * 128, f0 = blockIdx.x * 128;

    {
        const float4* src = (const float4*)(rw + (size_t)m0 * NEXP);
        ((float4*)rws)[tid] = src[tid];
    }

    const floatx4 z4 = {0.f, 0.f, 0.f, 0.f};
    floatx4 facc[4][4];
    #pragma unroll
    for (int i = 0; i < 4; ++i) {
        #pragma unroll
        for (int j = 0; j < 4; ++j) facc[i][j] = z4;
    }

    int aslot[2][4], bslot[2][4];
    #pragma unroll
    for (int s = 0; s < 2; ++s) {
        #pragma unroll
        for (int f = 0; f < 4; ++f) {
            int ra = wm*64 + f*16 + l16;
            int rb = wn*64 + f*16 + l16;
            int grp = s*4 + quad;
            aslot[s][f] = ra*8 + ((grp ^ ra) & 7);
            bslot[s][f] = rb*8 + ((grp ^ rb) & 7);
        }
    }

    __syncthreads();  // rws visible

    float wcur[4][4];

    for (int e = 0; e < NEXP; ++e) {
        #pragma unroll
        for (int mf = 0; mf < 4; ++mf) {
            #pragma unroll
            for (int r = 0; r < 4; ++r) {
                float wn_ = fmaxf(rws[(wm*64 + mf*16 + quad*4 + r) * NEXP + e], 1e-20f);
                if (e > 0) {
                    float ratio = wcur[mf][r] / wn_;
                    #pragma unroll
                    for (int nf = 0; nf < 4; ++nf)
                        facc[mf][nf][r] *= ratio;
                }
                wcur[mf][r] = wn_;
            }
        }

        for (int k0 = 0; k0 < DDIM; k0 += 64) {
            __syncthreads();
            #pragma unroll
            for (int t = 0; t < 4; ++t) {
                int g   = t * 256 + tid;
                int row = g >> 3;
                int c   = ((g ^ row) & 7) * 8;   // swizzled column group
                gload_lds16(hbf + (size_t)(m0 + row) * DDIM + k0 + c,
                            (char*)As + g * 16);
                gload_lds16(Bp + (size_t)(f0 + row) * KP + e * DDIM + k0 + c,
                            (char*)Bs + g * 16);
            }
            __syncthreads();

            #pragma unroll
            for (int s = 0; s < 2; ++s) {
                bf16x8 av[4], bv[4];
                #pragma unroll
                for (int mf = 0; mf < 4; ++mf)
                    av[mf] = *(const bf16x8*)&As[aslot[s][mf] * 8];
                #pragma unroll
                for (int nf = 0; nf < 4; ++nf)
                    bv[nf] = *(const bf16x8*)&Bs[bslot[s][nf] * 8];
                #pragma unroll
                for (int mf = 0; mf < 4; ++mf) {
                    #pragma unroll
                    for (int nf = 0; nf < 4; ++nf)
                        facc[mf][nf] = __builtin_amdgcn_mfma_f32_16x16x32_bf16(
                            av[mf], bv[nf], facc[mf][nf], 0, 0, 0);
                }
            }
        }
    }

    #pragma unroll
    for (int nf = 0; nf < 4; ++nf) {
        int gf = f0 + wn*64 + nf*16 + l16;
        float bval = bias[gf];
        #pragma unroll
        for (int mf = 0; mf < 4; ++mf) {
            int gm = m0 + wm*64 + mf*16 + quad*4;
            #pragma unroll
            for (int r = 0; r < 4; ++r) {
                float x = facc[mf][nf][r] * wcur[mf][r] + bval;
                float gel = 0.5f * x * (1.0f + erff(x * 0.70710678118f));
                outp[(size_t)(gm + r) * DDIM + gf] = gel;
            }
        }
    }
}

// ---------------------------------------------------------------------------
extern "C" void kernel_launch(void* const* d_in, const int* in_sizes, int n_in,
                              void* d_out, int out_size, void* d_ws, size_t ws_size,
                              hipStream_t stream) {
    const float* h    = (const float*)d_in[0];   // [4,4096,1024]
    const float* Wr   = (const float*)d_in[1];   // [8,1024]
    const float* br   = (const float*)d_in[2];   // [8]
    const float* We   = (const float*)d_in[3];   // [8,1024,1024]
    const float* bias = (const float*)d_in[4];   // [1024]
    float* outp = (float*)d_out;
    char* ws = (char*)d_ws;

    __bf16* hbf = (__bf16*)ws;                                   // 32 MiB
    __bf16* Bp  = (__bf16*)(ws + (size_t)M_TOK * DDIM * 2);      // 16 MiB
    float*  rwp = (float*)(ws + (size_t)M_TOK * DDIM * 2
                              + (size_t)NEXP * DDIM * DDIM * 2); // 512 KiB

    hipLaunchKernelGGL(prep_kernel, dim3(6144), dim3(256), 0, stream,
                       h, Wr, br, We, hbf, Bp, rwp);
    hipLaunchKernelGGL(gemm_fused_kernel, dim3(DDIM / 128, M_TOK / 128),
                       dim3(256), 0, stream, hbf, Bp, rwp, bias, outp);
}